// Round 9
// baseline (202.075 us; speedup 1.0000x reference)
//
#include <hip/hip_runtime.h>
#include <hip/hip_bf16.h>
#include <math.h>

#define S_   64
#define BS_  8
#define NN_  32
#define R_   8
#define H_   512
#define EMB_ 256
#define NT_  16384
#define KT3  2112     // 2048 + 64-pad bias block
#define NS3  33       // K-steps of 64
#define SCALE_ 0.35355339059327373f

typedef __attribute__((ext_vector_type(8))) short bf16x8;
typedef __attribute__((ext_vector_type(4))) float f32x4;
typedef __attribute__((ext_vector_type(4))) int i32x4;

__device__ __forceinline__ float gelu_exact(float x) {
    return 0.5f * x * (1.0f + erff(x * 0.70710678118654752440f));
}
// tanh-form gelu (max err ~3e-4). e-chain since r3; energy epilogue since r8.
__device__ __forceinline__ float gelu_fast(float x) {
    float inner = 0.7978845608028654f * fmaf(0.044715f * x, x * x, x);
    float e = __expf(2.0f * inner);
    return x * (1.0f - __builtin_amdgcn_rcpf(e + 1.0f));
}
__device__ __forceinline__ unsigned short f2bf(float v) {
    union { float f; unsigned int u; } c; c.f = v;
    unsigned int lsb = (c.u >> 16) & 1;
    c.u += 0x7fff + lsb;
    return (unsigned short)(c.u >> 16);
}
__device__ __forceinline__ int pack2bf(float a, float b) {
    return (int)((unsigned)f2bf(a) | ((unsigned)f2bf(b) << 16));
}
__device__ __forceinline__ i32x4 bf8_scale(i32x4 v, float p) {
    i32x4 out;
#pragma unroll
    for (int q = 0; q < 4; ++q) {
        unsigned u = (unsigned)v[q];
        float lo = __uint_as_float(u << 16);
        float hi = __uint_as_float(u & 0xffff0000u);
        out[q] = pack2bf(lo * p, hi * p);
    }
    return out;
}

// ---------------------------------------------------------------------------
// prep_all: bf16 copies of wl_w/wr_w (4096), pe table (65), e0 (8), E0 (64).
__global__ __launch_bounds__(256) void prep_all(
        const int* __restrict__ nid, const float* __restrict__ node_emb,
        const float* __restrict__ wl_w, const float* __restrict__ wr_w,
        const float* __restrict__ node_bias,
        float* __restrict__ pe, float* __restrict__ e_all,
        unsigned short* __restrict__ Wl_bf, unsigned short* __restrict__ Wr_bf,
        unsigned short* __restrict__ E0) {
    int blk = blockIdx.x, t = threadIdx.x;
    if (blk < 4096) {
        Wl_bf[(size_t)blk * 256 + t] = f2bf(wl_w[(size_t)blk * 256 + t]);
        Wr_bf[(size_t)blk * 256 + t] = f2bf(wr_w[(size_t)blk * 256 + t]);
    } else if (blk < 4161) {
        int p = blk - 4096, j = t;
        double ex = (double)(2 * j) / 512.0;
        float divf = (float)exp(ex * 9.210340371976184);
        float ang = (float)p * divf;
        double a = (double)ang;
        pe[p * H_ + 2 * j]     = (float)sin(a);
        pe[p * H_ + 2 * j + 1] = (float)cos(a);
    } else if (blk < 4169) {
        int b = blk - 4161;
        int src0 = nid[((b * S_ + 0) * NN_ + 0) * 2 + 0];
        for (int h = t; h < H_; h += 256) {
            float pe0 = (h & 1) ? 1.0f : 0.0f;   // pe[0] = [sin0,cos0,...]
            float g = gelu_fast(node_bias[(size_t)src0 * H_ + h]);
            e_all[b * H_ + h] = gelu_fast(g + pe0);
        }
    } else {
        int blk0 = blk - 4169;                    // 64 blocks, E0 gather
        int row = blk0 * 16 + (t >> 4);
        int u = t & 15;
        int uv = row >> 9, pair = row & 511;
        int i = pair >> 3, b = pair & 7;
        int id = nid[((b * S_ + i) * NN_ + 0) * 2 + uv];
        const float4* src = (const float4*)(node_emb + (size_t)id * EMB_ + u * 16);
        unsigned short* dst = E0 + (size_t)row * EMB_ + u * 16;
#pragma unroll
        for (int q = 0; q < 2; ++q) {
            float4 f0 = src[2 * q], f1 = src[2 * q + 1];
            i32x4 o;
            o[0] = pack2bf(f0.x, f0.y); o[1] = pack2bf(f0.z, f0.w);
            o[2] = pack2bf(f1.x, f1.y); o[3] = pack2bf(f1.z, f1.w);
            *(i32x4*)(dst + q * 8) = o;
        }
    }
}

// ---------------------------------------------------------------------------
// Dual-tensor GEMM C = A@B^T (+bias), 128x128 tile, BK=64, 4 waves.
__global__ __launch_bounds__(256) void gemm_nt(
        const unsigned short* __restrict__ A0, const unsigned short* __restrict__ B0,
        const float* __restrict__ bias0, float* __restrict__ C0,
        const unsigned short* __restrict__ A1, const unsigned short* __restrict__ B1,
        const float* __restrict__ bias1, float* __restrict__ C1,
        int K, int ldC) {
    const unsigned short* A = blockIdx.z ? A1 : A0;
    const unsigned short* B = blockIdx.z ? B1 : B0;
    const float* bias = blockIdx.z ? bias1 : bias0;
    float* C = blockIdx.z ? C1 : C0;
    __shared__ unsigned short Als[128 * 64];
    __shared__ unsigned short Bls[128 * 64];
    int bM = blockIdx.x, bN = blockIdx.y;
    int t = threadIdx.x, w = t >> 6, l = t & 63;
    const unsigned short* Ag = A + (size_t)bM * 128 * K;
    const unsigned short* Bg = B + (size_t)bN * 128 * K;
    int srow = t >> 1, shalf = t & 1;
    size_t sgoff = (size_t)srow * K + shalf * 32;
    int nks = K >> 6;
    f32x4 acc[2][8];
#pragma unroll
    for (int m = 0; m < 2; ++m)
#pragma unroll
        for (int r = 0; r < 8; ++r) acc[m][r] = (f32x4)0.f;
    i32x4 ar[4], br[4];
    {
        const i32x4* ap = (const i32x4*)(Ag + sgoff);
        const i32x4* bp = (const i32x4*)(Bg + sgoff);
#pragma unroll
        for (int q = 0; q < 4; ++q) { ar[q] = ap[q]; br[q] = bp[q]; }
    }
    const int swz = (srow & 7) << 4;
    const int wbase = srow * 128;
    for (int ks = 0; ks < nks; ++ks) {
        __syncthreads();
#pragma unroll
        for (int q = 0; q < 4; ++q) {
            int ba = wbase + ((shalf * 64 + q * 16) ^ swz);
            *(i32x4*)((char*)Als + ba) = ar[q];
            *(i32x4*)((char*)Bls + ba) = br[q];
        }
        __syncthreads();
        if (ks + 1 < nks) {
            const i32x4* ap = (const i32x4*)(Ag + sgoff + (ks + 1) * 64);
            const i32x4* bp = (const i32x4*)(Bg + sgoff + (ks + 1) * 64);
#pragma unroll
            for (int q = 0; q < 4; ++q) { ar[q] = ap[q]; br[q] = bp[q]; }
        }
#pragma unroll
        for (int kk2 = 0; kk2 < 2; ++kk2) {
            bf16x8 af[2], bf[8];
#pragma unroll
            for (int mf = 0; mf < 2; ++mf) {
                int row = w * 32 + mf * 16 + (l & 15);
                int ba = row * 128 + (((kk2 * 64) + ((l >> 4) * 16)) ^ ((row & 7) << 4));
                af[mf] = *(const bf16x8*)((const char*)Als + ba);
            }
#pragma unroll
            for (int r = 0; r < 8; ++r) {
                int row = r * 16 + (l & 15);
                int ba = row * 128 + (((kk2 * 64) + ((l >> 4) * 16)) ^ ((row & 7) << 4));
                bf[r] = *(const bf16x8*)((const char*)Bls + ba);
            }
#pragma unroll
            for (int mf = 0; mf < 2; ++mf)
#pragma unroll
                for (int r = 0; r < 8; ++r)
                    acc[mf][r] = __builtin_amdgcn_mfma_f32_16x16x32_bf16(
                        af[mf], bf[r], acc[mf][r], 0, 0, 0);
        }
    }
    float bv[8];
#pragma unroll
    for (int nf = 0; nf < 8; ++nf)
        bv[nf] = bias ? bias[bN * 128 + nf * 16 + (l & 15)] : 0.f;
#pragma unroll
    for (int mf = 0; mf < 2; ++mf)
#pragma unroll
        for (int nf = 0; nf < 8; ++nf)
#pragma unroll
            for (int reg = 0; reg < 4; ++reg) {
                int row = bM * 128 + w * 32 + mf * 16 + (l >> 4) * 4 + reg;
                int col = bN * 128 + nf * 16 + (l & 15);
                C[(size_t)row * ldC + col] = acc[mf][nf][reg] + bv[nf];
            }
}

// ---------------------------------------------------------------------------
// seq_prep: blocks 0-7 = single-wave sequential chains; 8-519 W3 build;
// 520-775 WlT transpose; 776-1287 Etgt gather (+tgt_ids).
__global__ __launch_bounds__(256, 1) void seq_prep(
        const int* __restrict__ nid, const float* __restrict__ positions,
        const float* __restrict__ U0, const float* __restrict__ V0,
        const float* __restrict__ bias_base, const float* __restrict__ node_bias,
        const float* __restrict__ pe, float* __restrict__ e_all,
        unsigned short* __restrict__ e_bf,
        const float* __restrict__ wr_w, const float* __restrict__ wr_b,
        unsigned short* __restrict__ W3,
        const float* __restrict__ wl_w, unsigned short* __restrict__ WlT,
        const float* __restrict__ node_emb,
        unsigned short* __restrict__ Etgt, int* __restrict__ tgt_ids) {
    int blk = blockIdx.x;
    int t = threadIdx.x;
    if (blk < 8) {
        if (t >= 64) return;
        __shared__ float w_s[64], inv_s[64];
        int b = blk, l = t;
        float wv = __expf(positions[l]);
        float ps = wv;
#pragma unroll
        for (int d = 1; d < 64; d <<= 1) {
            float o = __shfl_up(ps, d, 64);
            if (l >= d) ps += o;
        }
        w_s[l] = wv;
        inv_s[l] = 1.0f / ps;

        float uA[8][8], uB[8][8];
        float nbA[8], nbB[8], peA[8], peB[8], bb[8], er[8], run[8];
        {
            size_t b0 = (size_t)b * 4096 + l * 8;
#pragma unroll
            for (int r = 0; r < 8; ++r) {
                float4 a0 = *(const float4*)&U0[b0 + r * H_];
                float4 a1 = *(const float4*)&U0[b0 + r * H_ + 4];
                uA[r][0] = a0.x; uA[r][1] = a0.y; uA[r][2] = a0.z; uA[r][3] = a0.w;
                uA[r][4] = a1.x; uA[r][5] = a1.y; uA[r][6] = a1.z; uA[r][7] = a1.w;
            }
            int tgt0 = nid[((b * S_) * NN_) * 2 + 1];
            float4 n0 = *(const float4*)&node_bias[(size_t)tgt0 * H_ + l * 8];
            float4 n1 = *(const float4*)&node_bias[(size_t)tgt0 * H_ + l * 8 + 4];
            nbA[0] = n0.x; nbA[1] = n0.y; nbA[2] = n0.z; nbA[3] = n0.w;
            nbA[4] = n1.x; nbA[5] = n1.y; nbA[6] = n1.z; nbA[7] = n1.w;
            float4 p0 = *(const float4*)&pe[H_ + l * 8];
            float4 p1 = *(const float4*)&pe[H_ + l * 8 + 4];
            peA[0] = p0.x; peA[1] = p0.y; peA[2] = p0.z; peA[3] = p0.w;
            peA[4] = p1.x; peA[5] = p1.y; peA[6] = p1.z; peA[7] = p1.w;
            float4 c0 = *(const float4*)&bias_base[l * 8];
            float4 c1 = *(const float4*)&bias_base[l * 8 + 4];
            bb[0] = c0.x; bb[1] = c0.y; bb[2] = c0.z; bb[3] = c0.w;
            bb[4] = c1.x; bb[5] = c1.y; bb[6] = c1.z; bb[7] = c1.w;
            float4 e0v = *(const float4*)&e_all[b * H_ + l * 8];
            float4 e1v = *(const float4*)&e_all[b * H_ + l * 8 + 4];
            er[0] = e0v.x; er[1] = e0v.y; er[2] = e0v.z; er[3] = e0v.w;
            er[4] = e1v.x; er[5] = e1v.y; er[6] = e1v.z; er[7] = e1v.w;
#pragma unroll
            for (int j = 0; j < 8; ++j) run[j] = 0.f;
        }
        auto step = [&](float (&uc)[8][8], float (&un)[8][8],
                        float (&nbc)[8], float (&nbn)[8],
                        float (&pc)[8], float (&pn)[8], int i) {
            if (i + 1 < S_) {
                size_t bn = ((size_t)(i + 1) * BS_ + b) * 4096 + l * 8;
#pragma unroll
                for (int r = 0; r < 8; ++r) {
                    float4 a0 = *(const float4*)&U0[bn + r * H_];
                    float4 a1 = *(const float4*)&U0[bn + r * H_ + 4];
                    un[r][0] = a0.x; un[r][1] = a0.y; un[r][2] = a0.z; un[r][3] = a0.w;
                    un[r][4] = a1.x; un[r][5] = a1.y; un[r][6] = a1.z; un[r][7] = a1.w;
                }
                int tgtn = nid[((b * S_ + i + 1) * NN_) * 2 + 1];
                float4 n0 = *(const float4*)&node_bias[(size_t)tgtn * H_ + l * 8];
                float4 n1 = *(const float4*)&node_bias[(size_t)tgtn * H_ + l * 8 + 4];
                nbn[0] = n0.x; nbn[1] = n0.y; nbn[2] = n0.z; nbn[3] = n0.w;
                nbn[4] = n1.x; nbn[5] = n1.y; nbn[6] = n1.z; nbn[7] = n1.w;
                float4 p0 = *(const float4*)&pe[(i + 2) * H_ + l * 8];
                float4 p1 = *(const float4*)&pe[(i + 2) * H_ + l * 8 + 4];
                pn[0] = p0.x; pn[1] = p0.y; pn[2] = p0.z; pn[3] = p0.w;
                pn[4] = p1.x; pn[5] = p1.y; pn[6] = p1.z; pn[7] = p1.w;
            }
            float v[8][8];
            size_t bc = ((size_t)i * BS_ + b) * 4096 + l * 8;
#pragma unroll
            for (int r = 0; r < 8; ++r) {
                float4 a0 = *(const float4*)&V0[bc + r * H_];
                float4 a1 = *(const float4*)&V0[bc + r * H_ + 4];
                v[r][0] = a0.x; v[r][1] = a0.y; v[r][2] = a0.z; v[r][3] = a0.w;
                v[r][4] = a1.x; v[r][5] = a1.y; v[r][6] = a1.z; v[r][7] = a1.w;
            }
            size_t eo = ((size_t)i * BS_ + b) * H_ + l * 8;
            *(float4*)&e_all[eo]     = make_float4(er[0], er[1], er[2], er[3]);
            *(float4*)&e_all[eo + 4] = make_float4(er[4], er[5], er[6], er[7]);
            i32x4 ep;
            ep[0] = pack2bf(er[0], er[1]); ep[1] = pack2bf(er[2], er[3]);
            ep[2] = pack2bf(er[4], er[5]); ep[3] = pack2bf(er[6], er[7]);
            *(i32x4*)&e_bf[eo] = ep;
            float pr[8];
#pragma unroll
            for (int r = 0; r < 8; ++r) {
                float p = er[0] * uc[r][0];
#pragma unroll
                for (int j = 1; j < 8; ++j) p = fmaf(er[j], uc[r][j], p);
                pr[r] = p;
            }
#pragma unroll
            for (int mask = 1; mask < 64; mask <<= 1)
#pragma unroll
                for (int r = 0; r < 8; ++r) pr[r] += __shfl_xor(pr[r], mask, 64);
            float wi = w_s[i], inv = inv_s[i];
#pragma unroll
            for (int j = 0; j < 8; ++j) {
                float nx = pr[0] * v[0][j];
#pragma unroll
                for (int r = 1; r < 8; ++r) nx = fmaf(pr[r], v[r][j], nx);
                float val = fmaf(nx, SCALE_, bb[j] + nbc[j] + pc[j]);
                float o = gelu_fast(val);
                run[j] = fmaf(wi, o, run[j]);
                er[j] = run[j] * inv;
            }
        };
        for (int i = 0; i < S_; i += 2) {
            step(uA, uB, nbA, nbB, peA, peB, i);
            step(uB, uA, nbB, nbA, peB, peA, i + 1);
        }
    } else if (blk < 520) {
        // ---- W3[h][k] build (coalesced: lanes stride k) ----
        int h = blk - 8;
        for (int k = t; k < KT3; k += 256) {
            float v;
            if (k < 2048)       v = wr_w[(size_t)((k >> 8) * H_ + h) * EMB_ + (k & 255)];
            else if (k < 2056)  v = wr_b[(size_t)(k - 2048) * H_ + h];
            else                v = 0.f;
            W3[(size_t)h * KT3 + k] = f2bf(v);
        }
    } else if (blk < 776) {
        // ---- WlT transpose ----
        __shared__ float tile[64][65];
        int b2 = blk - 520;
        int r = b2 >> 5, hb = (b2 >> 2) & 7, cb = b2 & 3;
#pragma unroll
        for (int it = 0; it < 16; ++it) {
            int idx = it * 256 + t;
            int hl = idx >> 6, cl = idx & 63;
            tile[hl][cl] = wl_w[(size_t)(r * H_ + hb * 64 + hl) * EMB_ + cb * 64 + cl];
        }
        __syncthreads();
#pragma unroll
        for (int it = 0; it < 16; ++it) {
            int idx = it * 256 + t;
            int cl = idx >> 6, hl = idx & 63;
            WlT[(size_t)(r * EMB_ + cb * 64 + cl) * H_ + hb * 64 + hl] = f2bf(tile[hl][cl]);
        }
    } else {
        // ---- Etgt gather + tgt_ids ----
        int b3 = blk - 776;
        int trip = b3 * 32 + (t >> 3);
        int u = t & 7;
        int i = trip >> 8, b = (trip >> 5) & 7, n = trip & 31;
        int id = nid[((b * S_ + i) * NN_ + n) * 2 + 1];
        if (u == 0) tgt_ids[trip] = id;
        const float4* src = (const float4*)(node_emb + (size_t)id * EMB_ + u * 32);
        unsigned short* dst = Etgt + (size_t)trip * EMB_ + u * 32;
#pragma unroll
        for (int q = 0; q < 4; ++q) {
            float4 f0 = src[2 * q], f1 = src[2 * q + 1];
            i32x4 o;
            o[0] = pack2bf(f0.x, f0.y); o[1] = pack2bf(f0.z, f0.w);
            o[2] = pack2bf(f1.x, f1.y); o[3] = pack2bf(f1.z, f1.w);
            *(i32x4*)(dst + q * 8) = o;
        }
    }
}

// ---------------------------------------------------------------------------
// proj (cb folded): proj[trip][r] = A2[pair][r*256..]·emb_src + e·wl_b_r
__global__ __launch_bounds__(512) void proj_kernel(
        const int* __restrict__ nid, const float* __restrict__ node_emb,
        const float* __restrict__ A2, const float* __restrict__ e_all,
        const float* __restrict__ wl_b, float* __restrict__ proj) {
    __shared__ float A_s[R_][EMB_];
    __shared__ float cb_s[R_];
    int pair = blockIdx.x;
    int t = threadIdx.x;
    int w = t >> 6, l = t & 63;
    int i = pair >> 3, b = pair & 7;
#pragma unroll
    for (int q = 0; q < 4; ++q) {
        int idx = q * 512 + t;
        A_s[idx >> 8][idx & 255] = A2[(size_t)pair * 2048 + idx];
    }
    {
        float p = 0.f;
#pragma unroll
        for (int k = 0; k < 8; ++k) {
            int h = l + 64 * k;
            p = fmaf(e_all[(size_t)pair * H_ + h], wl_b[(size_t)w * H_ + h], p);
        }
#pragma unroll
        for (int mask = 1; mask < 64; mask <<= 1) p += __shfl_xor(p, mask, 64);
        if (l == 0) cb_s[w] = p;
    }
    __syncthreads();
    float4 a4 = ((const float4*)A_s[w])[l];
    int id = nid[((b * S_ + i) * NN_ + 0) * 2 + 0];
    float4 em = ((const float4*)(node_emb + (size_t)id * EMB_))[l];
    for (int n = 0; n < NN_; ++n) {
        float4 cur = em;
        if (n < NN_ - 1) {
            id = nid[((b * S_ + i) * NN_ + n + 1) * 2 + 0];
            em = ((const float4*)(node_emb + (size_t)id * EMB_))[l];
        }
        float p = cur.x * a4.x + cur.y * a4.y + cur.z * a4.z + cur.w * a4.w;
#pragma unroll
        for (int off = 32; off; off >>= 1) p += __shfl_down(p, off, 64);
        if (l == 0) proj[((size_t)pair * NN_ + n) * R_ + w] = p + cb_s[w];
    }
}

// ---------------------------------------------------------------------------
// gemm_v3: nxt = ê @ W3^T, ê built on the fly (proj ⊗ emb), K=2112.
// Round-9: 256 threads, BM=128 x BN=128, grid (128,4) -> 2 blocks/CU;
// double-buffered LDS (1 barrier/K-step); gemm_nt fragment geometry.
__global__ __launch_bounds__(256) void gemm_v3(
        const unsigned short* __restrict__ W3, const unsigned short* __restrict__ Etgt,
        const int* __restrict__ tgt_ids, const float* __restrict__ proj,
        const float* __restrict__ bias_base, const float* __restrict__ pe,
        const float* __restrict__ node_bias, float* __restrict__ epart) {
    __shared__ unsigned short Als[2][128 * 64];   // 32 KB
    __shared__ unsigned short Bls[2][128 * 64];   // 32 KB
    __shared__ float proj_s[128 * R_];            // 4 KB
    __shared__ float base_s[128];
    __shared__ int   tgt_s[128];
    int blkM = blockIdx.x;        // 0..127 (trip tiles)
    int blkN = blockIdx.y;        // 0..3   (h tiles of 128)
    int trip0 = blkM * 128;
    int i_blk = blkM >> 1;        // one i per 128-trip tile
    int t = threadIdx.x, w = t >> 6, l = t & 63;

    ((float4*)proj_s)[t] = ((const float4*)(proj + (size_t)trip0 * R_))[t];
    if (t < 128) {
        base_s[t] = bias_base[blkN * 128 + t] + pe[(i_blk + 1) * H_ + blkN * 128 + t];
        tgt_s[t] = tgt_ids[trip0 + t];
    }
    __syncthreads();

    int srow = t >> 1, shalf = t & 1;   // 128 rows x 2 half-rows (32 ushorts)
    const float* prow = proj_s + srow * R_;
    const unsigned short* Abase = Etgt + (size_t)(trip0 + srow) * EMB_ + shalf * 32;
    const unsigned short* Bbase = W3 + (size_t)(blkN * 128 + srow) * KT3 + shalf * 32;

    f32x4 acc[2][8];
#pragma unroll
    for (int m = 0; m < 2; ++m)
#pragma unroll
        for (int r = 0; r < 8; ++r) acc[m][r] = (f32x4)0.f;

    i32x4 ar[4], br[4];
#define A_LOAD(KS)                                                            \
    if ((KS) < 32) {                                                          \
        const i32x4* ap = (const i32x4*)(Abase + (((KS) & 3) << 6));          \
        _Pragma("unroll")                                                     \
        for (int q = 0; q < 4; ++q) ar[q] = ap[q];                            \
    }
#define B_LOAD(KS)                                                            \
    {                                                                         \
        const i32x4* bp = (const i32x4*)(Bbase + (KS) * 64);                  \
        _Pragma("unroll")                                                     \
        for (int q = 0; q < 4; ++q) br[q] = bp[q];                            \
    }
#define STORE(KS, BUF)                                                        \
    {                                                                         \
        i32x4 av[4];                                                          \
        if ((KS) < 32) {                                                      \
            float pf = prow[(KS) >> 2];                                       \
            _Pragma("unroll")                                                 \
            for (int q = 0; q < 4; ++q) av[q] = bf8_scale(ar[q], pf);         \
        } else {                                                              \
            _Pragma("unroll")                                                 \
            for (int q = 0; q < 4; ++q) av[q] = (i32x4)0;                     \
            if (shalf == 0) {                                                 \
                av[0][0] = pack2bf(prow[0], prow[1]);                         \
                av[0][1] = pack2bf(prow[2], prow[3]);                         \
                av[0][2] = pack2bf(prow[4], prow[5]);                         \
                av[0][3] = pack2bf(prow[6], prow[7]);                         \
            }                                                                 \
        }                                                                     \
        const int swz_ = (srow & 7) << 4;                                     \
        const int wb_ = srow * 128;                                           \
        _Pragma("unroll")                                                     \
        for (int q = 0; q < 4; ++q) {                                         \
            int ba = wb_ + ((shalf * 64 + q * 16) ^ swz_);                    \
            *(i32x4*)((char*)Als[BUF] + ba) = av[q];                          \
            *(i32x4*)((char*)Bls[BUF] + ba) = br[q];                         \
        }                                                                     \
    }

    A_LOAD(0); B_LOAD(0); STORE(0, 0);
    __syncthreads();
    for (int ks = 0; ks < NS3; ++ks) {
        if (ks + 1 < NS3) { A_LOAD(ks + 1); B_LOAD(ks + 1); }
        const char* Ab = (const char*)Als[ks & 1];
        const char* Bb = (const char*)Bls[ks & 1];
#pragma unroll
        for (int kk2 = 0; kk2 < 2; ++kk2) {
            bf16x8 af[2], bf[8];
#pragma unroll
            for (int mf = 0; mf < 2; ++mf) {
                int row = w * 32 + mf * 16 + (l & 15);
                int ba = row * 128 + (((kk2 * 64) + ((l >> 4) * 16)) ^ ((row & 7) << 4));
                af[mf] = *(const bf16x8*)(Ab + ba);
            }
#pragma unroll
            for (int r = 0; r < 8; ++r) {
                int row = r * 16 + (l & 15);
                int ba = row * 128 + (((kk2 * 64) + ((l >> 4) * 16)) ^ ((row & 7) << 4));
                bf[r] = *(const bf16x8*)(Bb + ba);
            }
#pragma unroll
            for (int mf = 0; mf < 2; ++mf)
#pragma unroll
                for (int r = 0; r < 8; ++r)
                    acc[mf][r] = __builtin_amdgcn_mfma_f32_16x16x32_bf16(
                        af[mf], bf[r], acc[mf][r], 0, 0, 0);
        }
        if (ks + 1 < NS3) STORE(ks + 1, (ks + 1) & 1);
        __syncthreads();
    }
#undef A_LOAD
#undef B_LOAD
#undef STORE

    // epilogue: gelu(nxt*SCALE+base+node_bias)^2, reduce over block's 128 h
    int hl = l & 15, lq = l >> 4;
#pragma unroll
    for (int mf = 0; mf < 2; ++mf)
#pragma unroll
        for (int reg = 0; reg < 4; ++reg) {
            int tl = w * 32 + mf * 16 + lq * 4 + reg;
            int tgt = tgt_s[tl];
            float s = 0.f;
#pragma unroll
            for (int nf = 0; nf < 8; ++nf) {
                int hloc = nf * 16 + hl;
                int h = blkN * 128 + hloc;
                float val = fmaf(acc[mf][nf][reg], SCALE_,
                                 base_s[hloc] + node_bias[(size_t)tgt * H_ + h]);
                float o = gelu_fast(val);
                s = fmaf(o, o, s);
            }
            s += __shfl_xor(s, 1, 64);
            s += __shfl_xor(s, 2, 64);
            s += __shfl_xor(s, 4, 64);
            s += __shfl_xor(s, 8, 64);
            if (hl == 0) epart[(size_t)(trip0 + tl) * 4 + blkN] = s;
        }
}

// ---------------------------------------------------------------------------
// loss (energy finalize folded in; epart has 4 partials per trip)
__global__ void loss_kernel(const float* __restrict__ epart, float* __restrict__ out) {
    __shared__ float red[8];
    int t = threadIdx.x;  // 512 pairs
    float en[NN_];
    float mx = -1e30f;
#pragma unroll
    for (int n = 0; n < NN_; ++n) {
        int trip = t * NN_ + n;
        float4 q = *(const float4*)&epart[(size_t)trip * 4];
        en[n] = sqrtf(q.x + q.y + q.z + q.w);
        mx = fmaxf(mx, en[n]);
    }
    float s = 0.f;
#pragma unroll
    for (int n = 0; n < NN_; ++n) s += expf(en[n] - mx);
    float li = logf(s) + mx - en[0];
#pragma unroll
    for (int off = 32; off; off >>= 1) li += __shfl_down(li, off, 64);
    if ((t & 63) == 0) red[t >> 6] = li;
    __syncthreads();
    if (t == 0) {
        float tot = 0.f;
#pragma unroll
        for (int w = 0; w < 8; ++w) tot += red[w];
        out[0] = tot / 512.0f;
    }
}

// ---------------------------------------------------------------------------
extern "C" void kernel_launch(void* const* d_in, const int* in_sizes, int n_in,
                              void* d_out, int out_size, void* d_ws, size_t ws_size,
                              hipStream_t stream) {
    const int*   nid       = (const int*)d_in[0];
    const float* node_emb  = (const float*)d_in[1];
    const float* wl_w      = (const float*)d_in[2];
    const float* wl_b      = (const float*)d_in[3];
    const float* wr_w      = (const float*)d_in[4];
    const float* wr_b      = (const float*)d_in[5];
    const float* bias_base = (const float*)d_in[6];
    const float* node_bias = (const float*)d_in[7];
    const float* positions = (const float*)d_in[8];
    float* out = (float*)d_out;

    float* ws      = (float*)d_ws;
    float* pe      = ws;                        // 33280
    float* e_all   = pe + 65 * H_;              // 262144
    float* U0      = e_all + 512 * H_;          // 2097152
    float* V0      = U0 + 512 * 4096;           // 2097152
    float* A2      = V0 + 512 * 4096;           // 1048576
    float* proj    = A2 + 512 * 2048;           // 131072
    float* epart   = proj + NT_ * R_;           // 65536
    unsigned short* e_bf  = (unsigned short*)(epart + 4 * NT_);   // 262144 sh
    unsigned short* W3    = e_bf + 512 * H_;                      // 512*2112 sh
    unsigned short* Wl_bf = W3 + 512 * KT3;                       // 1048576 sh
    unsigned short* Wr_bf = Wl_bf + 4096 * EMB_;                  // 1048576 sh
    unsigned short* WlT   = Wr_bf + 4096 * EMB_;                  // 1048576 sh
    unsigned short* E0    = WlT + 2048 * H_;                      // 262144 sh
    unsigned short* Etgt  = E0 + 1024 * EMB_;                     // 4194304 sh
    int* tgt_ids = (int*)(Etgt + (size_t)NT_ * EMB_);             // 16384

    prep_all<<<4233, 256, 0, stream>>>(nid, node_emb, wl_w, wr_w, node_bias,
                                       pe, e_all, Wl_bf, Wr_bf, E0);
    gemm_nt<<<dim3(4, 32, 2), 256, 0, stream>>>(
        E0, Wl_bf, wl_b, U0,
        E0 + 512 * EMB_, Wr_bf, wr_b, V0, 256, 4096);
    seq_prep<<<8 + 512 + 256 + 512, 256, 0, stream>>>(
        nid, positions, U0, V0, bias_base, node_bias, pe, e_all, e_bf,
        wr_w, wr_b, W3, wl_w, WlT, node_emb, Etgt, tgt_ids);
    gemm_nt<<<dim3(4, 16, 1), 256, 0, stream>>>(
        e_bf, WlT, nullptr, A2, e_bf, WlT, nullptr, A2, 512, 2048);
    proj_kernel<<<512, 512, 0, stream>>>(nid, node_emb, A2, e_all, wl_b, proj);
    gemm_v3<<<dim3(128, 4), 256, 0, stream>>>(W3, Etgt, tgt_ids, proj,
                                              bias_base, pe, node_bias, epart);
    loss_kernel<<<1, 512, 0, stream>>>(epart, out);
}

// Round 10
// 191.088 us; speedup vs baseline: 1.0575x; 1.0575x over previous
//
#include <hip/hip_runtime.h>
#include <hip/hip_bf16.h>
#include <math.h>

#define S_   64
#define BS_  8
#define NN_  32
#define R_   8
#define H_   512
#define EMB_ 256
#define NT_  16384
#define KT3  2112     // 2048 + 64-pad bias block
#define NS3  33       // K-steps of 64
#define SCALE_ 0.35355339059327373f

typedef __attribute__((ext_vector_type(8))) short bf16x8;
typedef __attribute__((ext_vector_type(4))) float f32x4;
typedef __attribute__((ext_vector_type(4))) int i32x4;

__device__ __forceinline__ float gelu_exact(float x) {
    return 0.5f * x * (1.0f + erff(x * 0.70710678118654752440f));
}
// tanh-form gelu (max err ~3e-4). e-chain since r3; energy epilogue since r8.
__device__ __forceinline__ float gelu_fast(float x) {
    float inner = 0.7978845608028654f * fmaf(0.044715f * x, x * x, x);
    float e = __expf(2.0f * inner);
    return x * (1.0f - __builtin_amdgcn_rcpf(e + 1.0f));
}
__device__ __forceinline__ unsigned short f2bf(float v) {
    union { float f; unsigned int u; } c; c.f = v;
    unsigned int lsb = (c.u >> 16) & 1;
    c.u += 0x7fff + lsb;
    return (unsigned short)(c.u >> 16);
}
__device__ __forceinline__ int pack2bf(float a, float b) {
    return (int)((unsigned)f2bf(a) | ((unsigned)f2bf(b) << 16));
}
// hardware packed f32->bf16 (RNE, bit-identical to f2bf), lo16=a hi16=b.
// Inline-asm pattern validated round 6 (passed, absmax 0.0).
__device__ __forceinline__ int cvt_pk_bf16(float a, float b) {
    int r;
    asm("v_cvt_pk_bf16_f32 %0, %1, %2" : "=v"(r) : "v"(a), "v"(b));
    return r;
}
// scale 8 packed bf16 by f32 p, repack via hardware cvt_pk (round-10 edit)
__device__ __forceinline__ i32x4 bf8_scale(i32x4 v, float p) {
    i32x4 out;
#pragma unroll
    for (int q = 0; q < 4; ++q) {
        unsigned u = (unsigned)v[q];
        float lo = __uint_as_float(u << 16);
        float hi = __uint_as_float(u & 0xffff0000u);
        out[q] = cvt_pk_bf16(lo * p, hi * p);
    }
    return out;
}

// ---------------------------------------------------------------------------
// prep_all: bf16 copies of wl_w/wr_w (4096), pe table (65), e0 (8), E0 (64).
__global__ __launch_bounds__(256) void prep_all(
        const int* __restrict__ nid, const float* __restrict__ node_emb,
        const float* __restrict__ wl_w, const float* __restrict__ wr_w,
        const float* __restrict__ node_bias,
        float* __restrict__ pe, float* __restrict__ e_all,
        unsigned short* __restrict__ Wl_bf, unsigned short* __restrict__ Wr_bf,
        unsigned short* __restrict__ E0) {
    int blk = blockIdx.x, t = threadIdx.x;
    if (blk < 4096) {
        Wl_bf[(size_t)blk * 256 + t] = f2bf(wl_w[(size_t)blk * 256 + t]);
        Wr_bf[(size_t)blk * 256 + t] = f2bf(wr_w[(size_t)blk * 256 + t]);
    } else if (blk < 4161) {
        int p = blk - 4096, j = t;
        double ex = (double)(2 * j) / 512.0;
        float divf = (float)exp(ex * 9.210340371976184);
        float ang = (float)p * divf;
        double a = (double)ang;
        pe[p * H_ + 2 * j]     = (float)sin(a);
        pe[p * H_ + 2 * j + 1] = (float)cos(a);
    } else if (blk < 4169) {
        int b = blk - 4161;
        int src0 = nid[((b * S_ + 0) * NN_ + 0) * 2 + 0];
        for (int h = t; h < H_; h += 256) {
            float pe0 = (h & 1) ? 1.0f : 0.0f;   // pe[0] = [sin0,cos0,...]
            float g = gelu_fast(node_bias[(size_t)src0 * H_ + h]);
            e_all[b * H_ + h] = gelu_fast(g + pe0);
        }
    } else {
        int blk0 = blk - 4169;                    // 64 blocks, E0 gather
        int row = blk0 * 16 + (t >> 4);
        int u = t & 15;
        int uv = row >> 9, pair = row & 511;
        int i = pair >> 3, b = pair & 7;
        int id = nid[((b * S_ + i) * NN_ + 0) * 2 + uv];
        const float4* src = (const float4*)(node_emb + (size_t)id * EMB_ + u * 16);
        unsigned short* dst = E0 + (size_t)row * EMB_ + u * 16;
#pragma unroll
        for (int q = 0; q < 2; ++q) {
            float4 f0 = src[2 * q], f1 = src[2 * q + 1];
            i32x4 o;
            o[0] = pack2bf(f0.x, f0.y); o[1] = pack2bf(f0.z, f0.w);
            o[2] = pack2bf(f1.x, f1.y); o[3] = pack2bf(f1.z, f1.w);
            *(i32x4*)(dst + q * 8) = o;
        }
    }
}

// ---------------------------------------------------------------------------
// Dual-tensor GEMM C = A@B^T (+bias), 128x128 tile, BK=64, 4 waves.
__global__ __launch_bounds__(256) void gemm_nt(
        const unsigned short* __restrict__ A0, const unsigned short* __restrict__ B0,
        const float* __restrict__ bias0, float* __restrict__ C0,
        const unsigned short* __restrict__ A1, const unsigned short* __restrict__ B1,
        const float* __restrict__ bias1, float* __restrict__ C1,
        int K, int ldC) {
    const unsigned short* A = blockIdx.z ? A1 : A0;
    const unsigned short* B = blockIdx.z ? B1 : B0;
    const float* bias = blockIdx.z ? bias1 : bias0;
    float* C = blockIdx.z ? C1 : C0;
    __shared__ unsigned short Als[128 * 64];
    __shared__ unsigned short Bls[128 * 64];
    int bM = blockIdx.x, bN = blockIdx.y;
    int t = threadIdx.x, w = t >> 6, l = t & 63;
    const unsigned short* Ag = A + (size_t)bM * 128 * K;
    const unsigned short* Bg = B + (size_t)bN * 128 * K;
    int srow = t >> 1, shalf = t & 1;
    size_t sgoff = (size_t)srow * K + shalf * 32;
    int nks = K >> 6;
    f32x4 acc[2][8];
#pragma unroll
    for (int m = 0; m < 2; ++m)
#pragma unroll
        for (int r = 0; r < 8; ++r) acc[m][r] = (f32x4)0.f;
    i32x4 ar[4], br[4];
    {
        const i32x4* ap = (const i32x4*)(Ag + sgoff);
        const i32x4* bp = (const i32x4*)(Bg + sgoff);
#pragma unroll
        for (int q = 0; q < 4; ++q) { ar[q] = ap[q]; br[q] = bp[q]; }
    }
    const int swz = (srow & 7) << 4;
    const int wbase = srow * 128;
    for (int ks = 0; ks < nks; ++ks) {
        __syncthreads();
#pragma unroll
        for (int q = 0; q < 4; ++q) {
            int ba = wbase + ((shalf * 64 + q * 16) ^ swz);
            *(i32x4*)((char*)Als + ba) = ar[q];
            *(i32x4*)((char*)Bls + ba) = br[q];
        }
        __syncthreads();
        if (ks + 1 < nks) {
            const i32x4* ap = (const i32x4*)(Ag + sgoff + (ks + 1) * 64);
            const i32x4* bp = (const i32x4*)(Bg + sgoff + (ks + 1) * 64);
#pragma unroll
            for (int q = 0; q < 4; ++q) { ar[q] = ap[q]; br[q] = bp[q]; }
        }
#pragma unroll
        for (int kk2 = 0; kk2 < 2; ++kk2) {
            bf16x8 af[2], bf[8];
#pragma unroll
            for (int mf = 0; mf < 2; ++mf) {
                int row = w * 32 + mf * 16 + (l & 15);
                int ba = row * 128 + (((kk2 * 64) + ((l >> 4) * 16)) ^ ((row & 7) << 4));
                af[mf] = *(const bf16x8*)((const char*)Als + ba);
            }
#pragma unroll
            for (int r = 0; r < 8; ++r) {
                int row = r * 16 + (l & 15);
                int ba = row * 128 + (((kk2 * 64) + ((l >> 4) * 16)) ^ ((row & 7) << 4));
                bf[r] = *(const bf16x8*)((const char*)Bls + ba);
            }
#pragma unroll
            for (int mf = 0; mf < 2; ++mf)
#pragma unroll
                for (int r = 0; r < 8; ++r)
                    acc[mf][r] = __builtin_amdgcn_mfma_f32_16x16x32_bf16(
                        af[mf], bf[r], acc[mf][r], 0, 0, 0);
        }
    }
    float bv[8];
#pragma unroll
    for (int nf = 0; nf < 8; ++nf)
        bv[nf] = bias ? bias[bN * 128 + nf * 16 + (l & 15)] : 0.f;
#pragma unroll
    for (int mf = 0; mf < 2; ++mf)
#pragma unroll
        for (int nf = 0; nf < 8; ++nf)
#pragma unroll
            for (int reg = 0; reg < 4; ++reg) {
                int row = bM * 128 + w * 32 + mf * 16 + (l >> 4) * 4 + reg;
                int col = bN * 128 + nf * 16 + (l & 15);
                C[(size_t)row * ldC + col] = acc[mf][nf][reg] + bv[nf];
            }
}

// ---------------------------------------------------------------------------
// seq_prep: blocks 0-7 = single-wave sequential chains; 8-519 W3 build;
// 520-775 WlT transpose; 776-1287 Etgt gather (+tgt_ids).
__global__ __launch_bounds__(256, 1) void seq_prep(
        const int* __restrict__ nid, const float* __restrict__ positions,
        const float* __restrict__ U0, const float* __restrict__ V0,
        const float* __restrict__ bias_base, const float* __restrict__ node_bias,
        const float* __restrict__ pe, float* __restrict__ e_all,
        unsigned short* __restrict__ e_bf,
        const float* __restrict__ wr_w, const float* __restrict__ wr_b,
        unsigned short* __restrict__ W3,
        const float* __restrict__ wl_w, unsigned short* __restrict__ WlT,
        const float* __restrict__ node_emb,
        unsigned short* __restrict__ Etgt, int* __restrict__ tgt_ids) {
    int blk = blockIdx.x;
    int t = threadIdx.x;
    if (blk < 8) {
        if (t >= 64) return;
        __shared__ float w_s[64], inv_s[64];
        int b = blk, l = t;
        float wv = __expf(positions[l]);
        float ps = wv;
#pragma unroll
        for (int d = 1; d < 64; d <<= 1) {
            float o = __shfl_up(ps, d, 64);
            if (l >= d) ps += o;
        }
        w_s[l] = wv;
        inv_s[l] = 1.0f / ps;

        float uA[8][8], uB[8][8];
        float nbA[8], nbB[8], peA[8], peB[8], bb[8], er[8], run[8];
        {
            size_t b0 = (size_t)b * 4096 + l * 8;
#pragma unroll
            for (int r = 0; r < 8; ++r) {
                float4 a0 = *(const float4*)&U0[b0 + r * H_];
                float4 a1 = *(const float4*)&U0[b0 + r * H_ + 4];
                uA[r][0] = a0.x; uA[r][1] = a0.y; uA[r][2] = a0.z; uA[r][3] = a0.w;
                uA[r][4] = a1.x; uA[r][5] = a1.y; uA[r][6] = a1.z; uA[r][7] = a1.w;
            }
            int tgt0 = nid[((b * S_) * NN_) * 2 + 1];
            float4 n0 = *(const float4*)&node_bias[(size_t)tgt0 * H_ + l * 8];
            float4 n1 = *(const float4*)&node_bias[(size_t)tgt0 * H_ + l * 8 + 4];
            nbA[0] = n0.x; nbA[1] = n0.y; nbA[2] = n0.z; nbA[3] = n0.w;
            nbA[4] = n1.x; nbA[5] = n1.y; nbA[6] = n1.z; nbA[7] = n1.w;
            float4 p0 = *(const float4*)&pe[H_ + l * 8];
            float4 p1 = *(const float4*)&pe[H_ + l * 8 + 4];
            peA[0] = p0.x; peA[1] = p0.y; peA[2] = p0.z; peA[3] = p0.w;
            peA[4] = p1.x; peA[5] = p1.y; peA[6] = p1.z; peA[7] = p1.w;
            float4 c0 = *(const float4*)&bias_base[l * 8];
            float4 c1 = *(const float4*)&bias_base[l * 8 + 4];
            bb[0] = c0.x; bb[1] = c0.y; bb[2] = c0.z; bb[3] = c0.w;
            bb[4] = c1.x; bb[5] = c1.y; bb[6] = c1.z; bb[7] = c1.w;
            float4 e0v = *(const float4*)&e_all[b * H_ + l * 8];
            float4 e1v = *(const float4*)&e_all[b * H_ + l * 8 + 4];
            er[0] = e0v.x; er[1] = e0v.y; er[2] = e0v.z; er[3] = e0v.w;
            er[4] = e1v.x; er[5] = e1v.y; er[6] = e1v.z; er[7] = e1v.w;
#pragma unroll
            for (int j = 0; j < 8; ++j) run[j] = 0.f;
        }
        auto step = [&](float (&uc)[8][8], float (&un)[8][8],
                        float (&nbc)[8], float (&nbn)[8],
                        float (&pc)[8], float (&pn)[8], int i) {
            if (i + 1 < S_) {
                size_t bn = ((size_t)(i + 1) * BS_ + b) * 4096 + l * 8;
#pragma unroll
                for (int r = 0; r < 8; ++r) {
                    float4 a0 = *(const float4*)&U0[bn + r * H_];
                    float4 a1 = *(const float4*)&U0[bn + r * H_ + 4];
                    un[r][0] = a0.x; un[r][1] = a0.y; un[r][2] = a0.z; un[r][3] = a0.w;
                    un[r][4] = a1.x; un[r][5] = a1.y; un[r][6] = a1.z; un[r][7] = a1.w;
                }
                int tgtn = nid[((b * S_ + i + 1) * NN_) * 2 + 1];
                float4 n0 = *(const float4*)&node_bias[(size_t)tgtn * H_ + l * 8];
                float4 n1 = *(const float4*)&node_bias[(size_t)tgtn * H_ + l * 8 + 4];
                nbn[0] = n0.x; nbn[1] = n0.y; nbn[2] = n0.z; nbn[3] = n0.w;
                nbn[4] = n1.x; nbn[5] = n1.y; nbn[6] = n1.z; nbn[7] = n1.w;
                float4 p0 = *(const float4*)&pe[(i + 2) * H_ + l * 8];
                float4 p1 = *(const float4*)&pe[(i + 2) * H_ + l * 8 + 4];
                pn[0] = p0.x; pn[1] = p0.y; pn[2] = p0.z; pn[3] = p0.w;
                pn[4] = p1.x; pn[5] = p1.y; pn[6] = p1.z; pn[7] = p1.w;
            }
            float v[8][8];
            size_t bc = ((size_t)i * BS_ + b) * 4096 + l * 8;
#pragma unroll
            for (int r = 0; r < 8; ++r) {
                float4 a0 = *(const float4*)&V0[bc + r * H_];
                float4 a1 = *(const float4*)&V0[bc + r * H_ + 4];
                v[r][0] = a0.x; v[r][1] = a0.y; v[r][2] = a0.z; v[r][3] = a0.w;
                v[r][4] = a1.x; v[r][5] = a1.y; v[r][6] = a1.z; v[r][7] = a1.w;
            }
            size_t eo = ((size_t)i * BS_ + b) * H_ + l * 8;
            *(float4*)&e_all[eo]     = make_float4(er[0], er[1], er[2], er[3]);
            *(float4*)&e_all[eo + 4] = make_float4(er[4], er[5], er[6], er[7]);
            i32x4 ep;
            ep[0] = pack2bf(er[0], er[1]); ep[1] = pack2bf(er[2], er[3]);
            ep[2] = pack2bf(er[4], er[5]); ep[3] = pack2bf(er[6], er[7]);
            *(i32x4*)&e_bf[eo] = ep;
            float pr[8];
#pragma unroll
            for (int r = 0; r < 8; ++r) {
                float p = er[0] * uc[r][0];
#pragma unroll
                for (int j = 1; j < 8; ++j) p = fmaf(er[j], uc[r][j], p);
                pr[r] = p;
            }
#pragma unroll
            for (int mask = 1; mask < 64; mask <<= 1)
#pragma unroll
                for (int r = 0; r < 8; ++r) pr[r] += __shfl_xor(pr[r], mask, 64);
            float wi = w_s[i], inv = inv_s[i];
#pragma unroll
            for (int j = 0; j < 8; ++j) {
                float nx = pr[0] * v[0][j];
#pragma unroll
                for (int r = 1; r < 8; ++r) nx = fmaf(pr[r], v[r][j], nx);
                float val = fmaf(nx, SCALE_, bb[j] + nbc[j] + pc[j]);
                float o = gelu_fast(val);
                run[j] = fmaf(wi, o, run[j]);
                er[j] = run[j] * inv;
            }
        };
        for (int i = 0; i < S_; i += 2) {
            step(uA, uB, nbA, nbB, peA, peB, i);
            step(uB, uA, nbB, nbA, peB, peA, i + 1);
        }
    } else if (blk < 520) {
        // ---- W3[h][k] build (coalesced: lanes stride k) ----
        int h = blk - 8;
        for (int k = t; k < KT3; k += 256) {
            float v;
            if (k < 2048)       v = wr_w[(size_t)((k >> 8) * H_ + h) * EMB_ + (k & 255)];
            else if (k < 2056)  v = wr_b[(size_t)(k - 2048) * H_ + h];
            else                v = 0.f;
            W3[(size_t)h * KT3 + k] = f2bf(v);
        }
    } else if (blk < 776) {
        // ---- WlT transpose ----
        __shared__ float tile[64][65];
        int b2 = blk - 520;
        int r = b2 >> 5, hb = (b2 >> 2) & 7, cb = b2 & 3;
#pragma unroll
        for (int it = 0; it < 16; ++it) {
            int idx = it * 256 + t;
            int hl = idx >> 6, cl = idx & 63;
            tile[hl][cl] = wl_w[(size_t)(r * H_ + hb * 64 + hl) * EMB_ + cb * 64 + cl];
        }
        __syncthreads();
#pragma unroll
        for (int it = 0; it < 16; ++it) {
            int idx = it * 256 + t;
            int cl = idx >> 6, hl = idx & 63;
            WlT[(size_t)(r * EMB_ + cb * 64 + cl) * H_ + hb * 64 + hl] = f2bf(tile[hl][cl]);
        }
    } else {
        // ---- Etgt gather + tgt_ids ----
        int b3 = blk - 776;
        int trip = b3 * 32 + (t >> 3);
        int u = t & 7;
        int i = trip >> 8, b = (trip >> 5) & 7, n = trip & 31;
        int id = nid[((b * S_ + i) * NN_ + n) * 2 + 1];
        if (u == 0) tgt_ids[trip] = id;
        const float4* src = (const float4*)(node_emb + (size_t)id * EMB_ + u * 32);
        unsigned short* dst = Etgt + (size_t)trip * EMB_ + u * 32;
#pragma unroll
        for (int q = 0; q < 4; ++q) {
            float4 f0 = src[2 * q], f1 = src[2 * q + 1];
            i32x4 o;
            o[0] = pack2bf(f0.x, f0.y); o[1] = pack2bf(f0.z, f0.w);
            o[2] = pack2bf(f1.x, f1.y); o[3] = pack2bf(f1.z, f1.w);
            *(i32x4*)(dst + q * 8) = o;
        }
    }
}

// ---------------------------------------------------------------------------
// proj (cb folded): proj[trip][r] = A2[pair][r*256..]·emb_src + e·wl_b_r
__global__ __launch_bounds__(512) void proj_kernel(
        const int* __restrict__ nid, const float* __restrict__ node_emb,
        const float* __restrict__ A2, const float* __restrict__ e_all,
        const float* __restrict__ wl_b, float* __restrict__ proj) {
    __shared__ float A_s[R_][EMB_];
    __shared__ float cb_s[R_];
    int pair = blockIdx.x;
    int t = threadIdx.x;
    int w = t >> 6, l = t & 63;
    int i = pair >> 3, b = pair & 7;
#pragma unroll
    for (int q = 0; q < 4; ++q) {
        int idx = q * 512 + t;
        A_s[idx >> 8][idx & 255] = A2[(size_t)pair * 2048 + idx];
    }
    {
        float p = 0.f;
#pragma unroll
        for (int k = 0; k < 8; ++k) {
            int h = l + 64 * k;
            p = fmaf(e_all[(size_t)pair * H_ + h], wl_b[(size_t)w * H_ + h], p);
        }
#pragma unroll
        for (int mask = 1; mask < 64; mask <<= 1) p += __shfl_xor(p, mask, 64);
        if (l == 0) cb_s[w] = p;
    }
    __syncthreads();
    float4 a4 = ((const float4*)A_s[w])[l];
    int id = nid[((b * S_ + i) * NN_ + 0) * 2 + 0];
    float4 em = ((const float4*)(node_emb + (size_t)id * EMB_))[l];
    for (int n = 0; n < NN_; ++n) {
        float4 cur = em;
        if (n < NN_ - 1) {
            id = nid[((b * S_ + i) * NN_ + n + 1) * 2 + 0];
            em = ((const float4*)(node_emb + (size_t)id * EMB_))[l];
        }
        float p = cur.x * a4.x + cur.y * a4.y + cur.z * a4.z + cur.w * a4.w;
#pragma unroll
        for (int off = 32; off; off >>= 1) p += __shfl_down(p, off, 64);
        if (l == 0) proj[((size_t)pair * NN_ + n) * R_ + w] = p + cb_s[w];
    }
}

// ---------------------------------------------------------------------------
// gemm_v3: nxt = ê @ W3^T, ê built on the fly (proj ⊗ emb), K=2112.
// r8 structure (512thr, BM128xBN256, dbuf, 1 barrier/K-step, gelu_fast);
// r10 edit: hardware v_cvt_pk_bf16_f32 in A-staging (bf8_scale + bias pack).
__global__ __launch_bounds__(512) void gemm_v3(
        const unsigned short* __restrict__ W3, const unsigned short* __restrict__ Etgt,
        const int* __restrict__ tgt_ids, const float* __restrict__ proj,
        const float* __restrict__ bias_base, const float* __restrict__ pe,
        const float* __restrict__ node_bias, float* __restrict__ epart) {
    __shared__ unsigned short Als[2][128 * 64];   // 32 KB
    __shared__ unsigned short Bls[2][256 * 64];   // 64 KB
    __shared__ float proj_s[128 * R_];            // 4 KB
    __shared__ float base_s[256];
    __shared__ float red_s[128 * 4];
    __shared__ int   tgt_s[128];
    int blkM = blockIdx.x;        // 0..127
    int blkN = blockIdx.y;        // 0..1
    int trip0 = blkM * 128;
    int i_blk = blkM >> 1;
    int t = threadIdx.x, w = t >> 6, l = t & 63;
    int wm = w >> 2, wn = w & 3;

    proj_s[t] = proj[(size_t)trip0 * R_ + t];
    proj_s[t + 512] = proj[(size_t)trip0 * R_ + t + 512];
    if (t < 256) base_s[t] = bias_base[blkN * 256 + t] + pe[(i_blk + 1) * H_ + blkN * 256 + t];
    if (t < 128) tgt_s[t] = tgt_ids[trip0 + t];
    __syncthreads();

    int srw = t >> 3, sun = t & 7;
    f32x4 acc[4][4];
#pragma unroll
    for (int m = 0; m < 4; ++m)
#pragma unroll
        for (int n = 0; n < 4; ++n) acc[m][n] = (f32x4)0.f;

    i32x4 ar[2], br[4];
#define A_LOAD(KS)                                                            \
    if ((KS) < 32) {                                                          \
        int c_ = (((KS) & 3) << 6) + (sun << 3);                              \
        _Pragma("unroll")                                                     \
        for (int q = 0; q < 2; ++q)                                           \
            ar[q] = *(const i32x4*)(Etgt + (size_t)(trip0 + q * 64 + srw) * EMB_ + c_); \
    }
#define B_LOAD(KS)                                                            \
    {                                                                         \
        _Pragma("unroll")                                                     \
        for (int q = 0; q < 4; ++q)                                           \
            br[q] = *(const i32x4*)(W3 + (size_t)(blkN * 256 + q * 64 + srw) * KT3 + (KS) * 64 + sun * 8); \
    }
#define STORE(KS, BUF)                                                        \
    {                                                                         \
        _Pragma("unroll")                                                     \
        for (int q = 0; q < 2; ++q) {                                         \
            int row = q * 64 + srw;                                           \
            i32x4 aval;                                                       \
            if ((KS) < 32) {                                                  \
                float pf = proj_s[row * R_ + ((KS) >> 2)];                    \
                aval = bf8_scale(ar[q], pf);                                  \
            } else if (sun == 0) {                                            \
                aval[0] = cvt_pk_bf16(proj_s[row * R_ + 0], proj_s[row * R_ + 1]); \
                aval[1] = cvt_pk_bf16(proj_s[row * R_ + 2], proj_s[row * R_ + 3]); \
                aval[2] = cvt_pk_bf16(proj_s[row * R_ + 4], proj_s[row * R_ + 5]); \
                aval[3] = cvt_pk_bf16(proj_s[row * R_ + 6], proj_s[row * R_ + 7]); \
            } else { aval[0] = 0; aval[1] = 0; aval[2] = 0; aval[3] = 0; }    \
            int ba = row * 128 + ((sun * 16) ^ ((row & 7) << 4));             \
            *(i32x4*)((char*)Als[BUF] + ba) = aval;                           \
        }                                                                     \
        _Pragma("unroll")                                                     \
        for (int q = 0; q < 4; ++q) {                                         \
            int row = q * 64 + srw;                                           \
            int ba = row * 128 + ((sun * 16) ^ ((row & 7) << 4));             \
            *(i32x4*)((char*)Bls[BUF] + ba) = br[q];                          \
        }                                                                     \
    }

    A_LOAD(0); B_LOAD(0); STORE(0, 0);
    __syncthreads();
    for (int ks = 0; ks < NS3; ++ks) {
        if (ks + 1 < NS3) { A_LOAD(ks + 1); B_LOAD(ks + 1); }
        const char* Ab = (const char*)Als[ks & 1];
        const char* Bb = (const char*)Bls[ks & 1];
#pragma unroll
        for (int kk2 = 0; kk2 < 2; ++kk2) {
            bf16x8 af[4], bf[4];
            int kb = kk2 * 64 + ((l >> 4) << 4);
#pragma unroll
            for (int mf = 0; mf < 4; ++mf) {
                int row = wm * 64 + mf * 16 + (l & 15);
                af[mf] = *(const bf16x8*)(Ab + row * 128 + (kb ^ ((row & 7) << 4)));
            }
#pragma unroll
            for (int nf = 0; nf < 4; ++nf) {
                int row = wn * 64 + nf * 16 + (l & 15);
                bf[nf] = *(const bf16x8*)(Bb + row * 128 + (kb ^ ((row & 7) << 4)));
            }
#pragma unroll
            for (int mf = 0; mf < 4; ++mf)
#pragma unroll
                for (int nf = 0; nf < 4; ++nf)
                    acc[mf][nf] = __builtin_amdgcn_mfma_f32_16x16x32_bf16(
                        af[mf], bf[nf], acc[mf][nf], 0, 0, 0);
        }
        if (ks + 1 < NS3) STORE(ks + 1, (ks + 1) & 1);
        __syncthreads();
    }
#undef A_LOAD
#undef B_LOAD
#undef STORE

    int hl = l & 15, lq = l >> 4;
#pragma unroll
    for (int mf = 0; mf < 4; ++mf)
#pragma unroll
        for (int reg = 0; reg < 4; ++reg) {
            int tl = wm * 64 + mf * 16 + lq * 4 + reg;
            int tgt = tgt_s[tl];
            float s = 0.f;
#pragma unroll
            for (int nf = 0; nf < 4; ++nf) {
                int hloc = wn * 64 + nf * 16 + hl;
                int h = blkN * 256 + hloc;
                float val = fmaf(acc[mf][nf][reg], SCALE_,
                                 base_s[hloc] + node_bias[(size_t)tgt * H_ + h]);
                float o = gelu_fast(val);
                s = fmaf(o, o, s);
            }
            s += __shfl_xor(s, 1, 64);
            s += __shfl_xor(s, 2, 64);
            s += __shfl_xor(s, 4, 64);
            s += __shfl_xor(s, 8, 64);
            if (hl == 0) red_s[tl * 4 + wn] = s;
        }
    __syncthreads();
    if (t < 128) {
        float s = red_s[t * 4] + red_s[t * 4 + 1] + red_s[t * 4 + 2] + red_s[t * 4 + 3];
        epart[(size_t)(trip0 + t) * 2 + blkN] = s;
    }
}

// ---------------------------------------------------------------------------
// loss (with energy finalize folded in)
__global__ void loss_kernel(const float* __restrict__ epart, float* __restrict__ out) {
    __shared__ float red[8];
    int t = threadIdx.x;  // 512 pairs
    float en[NN_];
    float mx = -1e30f;
#pragma unroll
    for (int n = 0; n < NN_; ++n) {
        int trip = t * NN_ + n;
        en[n] = sqrtf(epart[(size_t)trip * 2] + epart[(size_t)trip * 2 + 1]);
        mx = fmaxf(mx, en[n]);
    }
    float s = 0.f;
#pragma unroll
    for (int n = 0; n < NN_; ++n) s += expf(en[n] - mx);
    float li = logf(s) + mx - en[0];
#pragma unroll
    for (int off = 32; off; off >>= 1) li += __shfl_down(li, off, 64);
    if ((t & 63) == 0) red[t >> 6] = li;
    __syncthreads();
    if (t == 0) {
        float tot = 0.f;
#pragma unroll
        for (int w = 0; w < 8; ++w) tot += red[w];
        out[0] = tot / 512.0f;
    }
}

// ---------------------------------------------------------------------------
extern "C" void kernel_launch(void* const* d_in, const int* in_sizes, int n_in,
                              void* d_out, int out_size, void* d_ws, size_t ws_size,
                              hipStream_t stream) {
    const int*   nid       = (const int*)d_in[0];
    const float* node_emb  = (const float*)d_in[1];
    const float* wl_w      = (const float*)d_in[2];
    const float* wl_b      = (const float*)d_in[3];
    const float* wr_w      = (const float*)d_in[4];
    const float* wr_b      = (const float*)d_in[5];
    const float* bias_base = (const float*)d_in[6];
    const float* node_bias = (const float*)d_in[7];
    const float* positions = (const float*)d_in[8];
    float* out = (float*)d_out;

    float* ws      = (float*)d_ws;
    float* pe      = ws;                        // 33280
    float* e_all   = pe + 65 * H_;              // 262144
    float* U0      = e_all + 512 * H_;          // 2097152
    float* V0      = U0 + 512 * 4096;           // 2097152
    float* A2      = V0 + 512 * 4096;           // 1048576
    float* proj    = A2 + 512 * 2048;           // 131072
    float* epart   = proj + NT_ * R_;           // 32768
    unsigned short* e_bf  = (unsigned short*)(epart + 2 * NT_);   // 262144 sh
    unsigned short* W3    = e_bf + 512 * H_;                      // 512*2112 sh
    unsigned short* Wl_bf = W3 + 512 * KT3;                       // 1048576 sh
    unsigned short* Wr_bf = Wl_bf + 4096 * EMB_;                  // 1048576 sh
    unsigned short* WlT   = Wr_bf + 4096 * EMB_;                  // 1048576 sh
    unsigned short* E0    = WlT + 2048 * H_;                      // 262144 sh
    unsigned short* Etgt  = E0 + 1024 * EMB_;                     // 4194304 sh
    int* tgt_ids = (int*)(Etgt + (size_t)NT_ * EMB_);             // 16384

    prep_all<<<4233, 256, 0, stream>>>(nid, node_emb, wl_w, wr_w, node_bias,
                                       pe, e_all, Wl_bf, Wr_bf, E0);
    gemm_nt<<<dim3(4, 32, 2), 256, 0, stream>>>(
        E0, Wl_bf, wl_b, U0,
        E0 + 512 * EMB_, Wr_bf, wr_b, V0, 256, 4096);
    seq_prep<<<8 + 512 + 256 + 512, 256, 0, stream>>>(
        nid, positions, U0, V0, bias_base, node_bias, pe, e_all, e_bf,
        wr_w, wr_b, W3, wl_w, WlT, node_emb, Etgt, tgt_ids);
    gemm_nt<<<dim3(4, 16, 1), 256, 0, stream>>>(
        e_bf, WlT, nullptr, A2, e_bf, WlT, nullptr, A2, 512, 2048);
    proj_kernel<<<512, 512, 0, stream>>>(nid, node_emb, A2, e_all, wl_b, proj);
    gemm_v3<<<dim3(128, 2), 512, 0, stream>>>(W3, Etgt, tgt_ids, proj,
                                              bias_base, pe, node_bias, epart);
    loss_kernel<<<1, 512, 0, stream>>>(epart, out);
}

// Round 11
// 189.731 us; speedup vs baseline: 1.0651x; 1.0072x over previous
//
#include <hip/hip_runtime.h>
#include <hip/hip_bf16.h>
#include <math.h>

#define S_   64
#define BS_  8
#define NN_  32
#define R_   8
#define H_   512
#define EMB_ 256
#define NT_  16384
#define KT3  2112     // 2048 + 64-pad bias block
#define NS3  33       // K-steps of 64
#define SCALE_ 0.35355339059327373f

typedef __attribute__((ext_vector_type(8))) short bf16x8;
typedef __attribute__((ext_vector_type(4))) float f32x4;
typedef __attribute__((ext_vector_type(4))) int i32x4;

__device__ __forceinline__ float gelu_exact(float x) {
    return 0.5f * x * (1.0f + erff(x * 0.70710678118654752440f));
}
// tanh-form gelu (max err ~3e-4). e-chain since r3; energy epilogue since r8.
__device__ __forceinline__ float gelu_fast(float x) {
    float inner = 0.7978845608028654f * fmaf(0.044715f * x, x * x, x);
    float e = __expf(2.0f * inner);
    return x * (1.0f - __builtin_amdgcn_rcpf(e + 1.0f));
}
__device__ __forceinline__ unsigned short f2bf(float v) {
    union { float f; unsigned int u; } c; c.f = v;
    unsigned int lsb = (c.u >> 16) & 1;
    c.u += 0x7fff + lsb;
    return (unsigned short)(c.u >> 16);
}
__device__ __forceinline__ int pack2bf(float a, float b) {
    return (int)((unsigned)f2bf(a) | ((unsigned)f2bf(b) << 16));
}
// hardware packed f32->bf16 (RNE, bit-identical to f2bf), lo16=a hi16=b.
__device__ __forceinline__ int cvt_pk_bf16(float a, float b) {
    int r;
    asm("v_cvt_pk_bf16_f32 %0, %1, %2" : "=v"(r) : "v"(a), "v"(b));
    return r;
}
// scale 8 packed bf16 by f32 p, repack via hardware cvt_pk
__device__ __forceinline__ i32x4 bf8_scale(i32x4 v, float p) {
    i32x4 out;
#pragma unroll
    for (int q = 0; q < 4; ++q) {
        unsigned u = (unsigned)v[q];
        float lo = __uint_as_float(u << 16);
        float hi = __uint_as_float(u & 0xffff0000u);
        out[q] = cvt_pk_bf16(lo * p, hi * p);
    }
    return out;
}

// ---------------------------------------------------------------------------
// prep_all: bf16 copies of wl_w/wr_w (4096), pe table (65), e0 (8), E0 (64).
__global__ __launch_bounds__(256) void prep_all(
        const int* __restrict__ nid, const float* __restrict__ node_emb,
        const float* __restrict__ wl_w, const float* __restrict__ wr_w,
        const float* __restrict__ node_bias,
        float* __restrict__ pe, float* __restrict__ e_all,
        unsigned short* __restrict__ Wl_bf, unsigned short* __restrict__ Wr_bf,
        unsigned short* __restrict__ E0) {
    int blk = blockIdx.x, t = threadIdx.x;
    if (blk < 4096) {
        Wl_bf[(size_t)blk * 256 + t] = f2bf(wl_w[(size_t)blk * 256 + t]);
        Wr_bf[(size_t)blk * 256 + t] = f2bf(wr_w[(size_t)blk * 256 + t]);
    } else if (blk < 4161) {
        int p = blk - 4096, j = t;
        double ex = (double)(2 * j) / 512.0;
        float divf = (float)exp(ex * 9.210340371976184);
        float ang = (float)p * divf;
        double a = (double)ang;
        pe[p * H_ + 2 * j]     = (float)sin(a);
        pe[p * H_ + 2 * j + 1] = (float)cos(a);
    } else if (blk < 4169) {
        int b = blk - 4161;
        int src0 = nid[((b * S_ + 0) * NN_ + 0) * 2 + 0];
        for (int h = t; h < H_; h += 256) {
            float pe0 = (h & 1) ? 1.0f : 0.0f;   // pe[0] = [sin0,cos0,...]
            float g = gelu_fast(node_bias[(size_t)src0 * H_ + h]);
            e_all[b * H_ + h] = gelu_fast(g + pe0);
        }
    } else {
        int blk0 = blk - 4169;                    // 64 blocks, E0 gather
        int row = blk0 * 16 + (t >> 4);
        int u = t & 15;
        int uv = row >> 9, pair = row & 511;
        int i = pair >> 3, b = pair & 7;
        int id = nid[((b * S_ + i) * NN_ + 0) * 2 + uv];
        const float4* src = (const float4*)(node_emb + (size_t)id * EMB_ + u * 16);
        unsigned short* dst = E0 + (size_t)row * EMB_ + u * 16;
#pragma unroll
        for (int q = 0; q < 2; ++q) {
            float4 f0 = src[2 * q], f1 = src[2 * q + 1];
            i32x4 o;
            o[0] = pack2bf(f0.x, f0.y); o[1] = pack2bf(f0.z, f0.w);
            o[2] = pack2bf(f1.x, f1.y); o[3] = pack2bf(f1.z, f1.w);
            *(i32x4*)(dst + q * 8) = o;
        }
    }
}

// ---------------------------------------------------------------------------
// Dual-tensor GEMM C = A@B^T (+bias), 128x128 tile, BK=64, 4 waves.
__global__ __launch_bounds__(256) void gemm_nt(
        const unsigned short* __restrict__ A0, const unsigned short* __restrict__ B0,
        const float* __restrict__ bias0, float* __restrict__ C0,
        const unsigned short* __restrict__ A1, const unsigned short* __restrict__ B1,
        const float* __restrict__ bias1, float* __restrict__ C1,
        int K, int ldC) {
    const unsigned short* A = blockIdx.z ? A1 : A0;
    const unsigned short* B = blockIdx.z ? B1 : B0;
    const float* bias = blockIdx.z ? bias1 : bias0;
    float* C = blockIdx.z ? C1 : C0;
    __shared__ unsigned short Als[128 * 64];
    __shared__ unsigned short Bls[128 * 64];
    int bM = blockIdx.x, bN = blockIdx.y;
    int t = threadIdx.x, w = t >> 6, l = t & 63;
    const unsigned short* Ag = A + (size_t)bM * 128 * K;
    const unsigned short* Bg = B + (size_t)bN * 128 * K;
    int srow = t >> 1, shalf = t & 1;
    size_t sgoff = (size_t)srow * K + shalf * 32;
    int nks = K >> 6;
    f32x4 acc[2][8];
#pragma unroll
    for (int m = 0; m < 2; ++m)
#pragma unroll
        for (int r = 0; r < 8; ++r) acc[m][r] = (f32x4)0.f;
    i32x4 ar[4], br[4];
    {
        const i32x4* ap = (const i32x4*)(Ag + sgoff);
        const i32x4* bp = (const i32x4*)(Bg + sgoff);
#pragma unroll
        for (int q = 0; q < 4; ++q) { ar[q] = ap[q]; br[q] = bp[q]; }
    }
    const int swz = (srow & 7) << 4;
    const int wbase = srow * 128;
    for (int ks = 0; ks < nks; ++ks) {
        __syncthreads();
#pragma unroll
        for (int q = 0; q < 4; ++q) {
            int ba = wbase + ((shalf * 64 + q * 16) ^ swz);
            *(i32x4*)((char*)Als + ba) = ar[q];
            *(i32x4*)((char*)Bls + ba) = br[q];
        }
        __syncthreads();
        if (ks + 1 < nks) {
            const i32x4* ap = (const i32x4*)(Ag + sgoff + (ks + 1) * 64);
            const i32x4* bp = (const i32x4*)(Bg + sgoff + (ks + 1) * 64);
#pragma unroll
            for (int q = 0; q < 4; ++q) { ar[q] = ap[q]; br[q] = bp[q]; }
        }
#pragma unroll
        for (int kk2 = 0; kk2 < 2; ++kk2) {
            bf16x8 af[2], bf[8];
#pragma unroll
            for (int mf = 0; mf < 2; ++mf) {
                int row = w * 32 + mf * 16 + (l & 15);
                int ba = row * 128 + (((kk2 * 64) + ((l >> 4) * 16)) ^ ((row & 7) << 4));
                af[mf] = *(const bf16x8*)((const char*)Als + ba);
            }
#pragma unroll
            for (int r = 0; r < 8; ++r) {
                int row = r * 16 + (l & 15);
                int ba = row * 128 + (((kk2 * 64) + ((l >> 4) * 16)) ^ ((row & 7) << 4));
                bf[r] = *(const bf16x8*)((const char*)Bls + ba);
            }
#pragma unroll
            for (int mf = 0; mf < 2; ++mf)
#pragma unroll
                for (int r = 0; r < 8; ++r)
                    acc[mf][r] = __builtin_amdgcn_mfma_f32_16x16x32_bf16(
                        af[mf], bf[r], acc[mf][r], 0, 0, 0);
        }
    }
    float bv[8];
#pragma unroll
    for (int nf = 0; nf < 8; ++nf)
        bv[nf] = bias ? bias[bN * 128 + nf * 16 + (l & 15)] : 0.f;
#pragma unroll
    for (int mf = 0; mf < 2; ++mf)
#pragma unroll
        for (int nf = 0; nf < 8; ++nf)
#pragma unroll
            for (int reg = 0; reg < 4; ++reg) {
                int row = bM * 128 + w * 32 + mf * 16 + (l >> 4) * 4 + reg;
                int col = bN * 128 + nf * 16 + (l & 15);
                C[(size_t)row * ldC + col] = acc[mf][nf][reg] + bv[nf];
            }
}

// ---------------------------------------------------------------------------
// seq_prep: blocks 0-7 = single-wave sequential chains; 8-519 W3 build;
// 520-775 WlT transpose; 776-1287 Etgt gather (+tgt_ids).
__global__ __launch_bounds__(256, 1) void seq_prep(
        const int* __restrict__ nid, const float* __restrict__ positions,
        const float* __restrict__ U0, const float* __restrict__ V0,
        const float* __restrict__ bias_base, const float* __restrict__ node_bias,
        const float* __restrict__ pe, float* __restrict__ e_all,
        unsigned short* __restrict__ e_bf,
        const float* __restrict__ wr_w, const float* __restrict__ wr_b,
        unsigned short* __restrict__ W3,
        const float* __restrict__ wl_w, unsigned short* __restrict__ WlT,
        const float* __restrict__ node_emb,
        unsigned short* __restrict__ Etgt, int* __restrict__ tgt_ids) {
    int blk = blockIdx.x;
    int t = threadIdx.x;
    if (blk < 8) {
        if (t >= 64) return;
        __shared__ float w_s[64], inv_s[64];
        int b = blk, l = t;
        float wv = __expf(positions[l]);
        float ps = wv;
#pragma unroll
        for (int d = 1; d < 64; d <<= 1) {
            float o = __shfl_up(ps, d, 64);
            if (l >= d) ps += o;
        }
        w_s[l] = wv;
        inv_s[l] = 1.0f / ps;

        float uA[8][8], uB[8][8];
        float nbA[8], nbB[8], peA[8], peB[8], bb[8], er[8], run[8];
        {
            size_t b0 = (size_t)b * 4096 + l * 8;
#pragma unroll
            for (int r = 0; r < 8; ++r) {
                float4 a0 = *(const float4*)&U0[b0 + r * H_];
                float4 a1 = *(const float4*)&U0[b0 + r * H_ + 4];
                uA[r][0] = a0.x; uA[r][1] = a0.y; uA[r][2] = a0.z; uA[r][3] = a0.w;
                uA[r][4] = a1.x; uA[r][5] = a1.y; uA[r][6] = a1.z; uA[r][7] = a1.w;
            }
            int tgt0 = nid[((b * S_) * NN_) * 2 + 1];
            float4 n0 = *(const float4*)&node_bias[(size_t)tgt0 * H_ + l * 8];
            float4 n1 = *(const float4*)&node_bias[(size_t)tgt0 * H_ + l * 8 + 4];
            nbA[0] = n0.x; nbA[1] = n0.y; nbA[2] = n0.z; nbA[3] = n0.w;
            nbA[4] = n1.x; nbA[5] = n1.y; nbA[6] = n1.z; nbA[7] = n1.w;
            float4 p0 = *(const float4*)&pe[H_ + l * 8];
            float4 p1 = *(const float4*)&pe[H_ + l * 8 + 4];
            peA[0] = p0.x; peA[1] = p0.y; peA[2] = p0.z; peA[3] = p0.w;
            peA[4] = p1.x; peA[5] = p1.y; peA[6] = p1.z; peA[7] = p1.w;
            float4 c0 = *(const float4*)&bias_base[l * 8];
            float4 c1 = *(const float4*)&bias_base[l * 8 + 4];
            bb[0] = c0.x; bb[1] = c0.y; bb[2] = c0.z; bb[3] = c0.w;
            bb[4] = c1.x; bb[5] = c1.y; bb[6] = c1.z; bb[7] = c1.w;
            float4 e0v = *(const float4*)&e_all[b * H_ + l * 8];
            float4 e1v = *(const float4*)&e_all[b * H_ + l * 8 + 4];
            er[0] = e0v.x; er[1] = e0v.y; er[2] = e0v.z; er[3] = e0v.w;
            er[4] = e1v.x; er[5] = e1v.y; er[6] = e1v.z; er[7] = e1v.w;
#pragma unroll
            for (int j = 0; j < 8; ++j) run[j] = 0.f;
        }
        auto step = [&](float (&uc)[8][8], float (&un)[8][8],
                        float (&nbc)[8], float (&nbn)[8],
                        float (&pc)[8], float (&pn)[8], int i) {
            if (i + 1 < S_) {
                size_t bn = ((size_t)(i + 1) * BS_ + b) * 4096 + l * 8;
#pragma unroll
                for (int r = 0; r < 8; ++r) {
                    float4 a0 = *(const float4*)&U0[bn + r * H_];
                    float4 a1 = *(const float4*)&U0[bn + r * H_ + 4];
                    un[r][0] = a0.x; un[r][1] = a0.y; un[r][2] = a0.z; un[r][3] = a0.w;
                    un[r][4] = a1.x; un[r][5] = a1.y; un[r][6] = a1.z; un[r][7] = a1.w;
                }
                int tgtn = nid[((b * S_ + i + 1) * NN_) * 2 + 1];
                float4 n0 = *(const float4*)&node_bias[(size_t)tgtn * H_ + l * 8];
                float4 n1 = *(const float4*)&node_bias[(size_t)tgtn * H_ + l * 8 + 4];
                nbn[0] = n0.x; nbn[1] = n0.y; nbn[2] = n0.z; nbn[3] = n0.w;
                nbn[4] = n1.x; nbn[5] = n1.y; nbn[6] = n1.z; nbn[7] = n1.w;
                float4 p0 = *(const float4*)&pe[(i + 2) * H_ + l * 8];
                float4 p1 = *(const float4*)&pe[(i + 2) * H_ + l * 8 + 4];
                pn[0] = p0.x; pn[1] = p0.y; pn[2] = p0.z; pn[3] = p0.w;
                pn[4] = p1.x; pn[5] = p1.y; pn[6] = p1.z; pn[7] = p1.w;
            }
            float v[8][8];
            size_t bc = ((size_t)i * BS_ + b) * 4096 + l * 8;
#pragma unroll
            for (int r = 0; r < 8; ++r) {
                float4 a0 = *(const float4*)&V0[bc + r * H_];
                float4 a1 = *(const float4*)&V0[bc + r * H_ + 4];
                v[r][0] = a0.x; v[r][1] = a0.y; v[r][2] = a0.z; v[r][3] = a0.w;
                v[r][4] = a1.x; v[r][5] = a1.y; v[r][6] = a1.z; v[r][7] = a1.w;
            }
            size_t eo = ((size_t)i * BS_ + b) * H_ + l * 8;
            *(float4*)&e_all[eo]     = make_float4(er[0], er[1], er[2], er[3]);
            *(float4*)&e_all[eo + 4] = make_float4(er[4], er[5], er[6], er[7]);
            i32x4 ep;
            ep[0] = pack2bf(er[0], er[1]); ep[1] = pack2bf(er[2], er[3]);
            ep[2] = pack2bf(er[4], er[5]); ep[3] = pack2bf(er[6], er[7]);
            *(i32x4*)&e_bf[eo] = ep;
            float pr[8];
#pragma unroll
            for (int r = 0; r < 8; ++r) {
                float p = er[0] * uc[r][0];
#pragma unroll
                for (int j = 1; j < 8; ++j) p = fmaf(er[j], uc[r][j], p);
                pr[r] = p;
            }
#pragma unroll
            for (int mask = 1; mask < 64; mask <<= 1)
#pragma unroll
                for (int r = 0; r < 8; ++r) pr[r] += __shfl_xor(pr[r], mask, 64);
            float wi = w_s[i], inv = inv_s[i];
#pragma unroll
            for (int j = 0; j < 8; ++j) {
                float nx = pr[0] * v[0][j];
#pragma unroll
                for (int r = 1; r < 8; ++r) nx = fmaf(pr[r], v[r][j], nx);
                float val = fmaf(nx, SCALE_, bb[j] + nbc[j] + pc[j]);
                float o = gelu_fast(val);
                run[j] = fmaf(wi, o, run[j]);
                er[j] = run[j] * inv;
            }
        };
        for (int i = 0; i < S_; i += 2) {
            step(uA, uB, nbA, nbB, peA, peB, i);
            step(uB, uA, nbB, nbA, peB, peA, i + 1);
        }
    } else if (blk < 520) {
        // ---- W3[h][k] build (coalesced: lanes stride k) ----
        int h = blk - 8;
        for (int k = t; k < KT3; k += 256) {
            float v;
            if (k < 2048)       v = wr_w[(size_t)((k >> 8) * H_ + h) * EMB_ + (k & 255)];
            else if (k < 2056)  v = wr_b[(size_t)(k - 2048) * H_ + h];
            else                v = 0.f;
            W3[(size_t)h * KT3 + k] = f2bf(v);
        }
    } else if (blk < 776) {
        // ---- WlT transpose ----
        __shared__ float tile[64][65];
        int b2 = blk - 520;
        int r = b2 >> 5, hb = (b2 >> 2) & 7, cb = b2 & 3;
#pragma unroll
        for (int it = 0; it < 16; ++it) {
            int idx = it * 256 + t;
            int hl = idx >> 6, cl = idx & 63;
            tile[hl][cl] = wl_w[(size_t)(r * H_ + hb * 64 + hl) * EMB_ + cb * 64 + cl];
        }
        __syncthreads();
#pragma unroll
        for (int it = 0; it < 16; ++it) {
            int idx = it * 256 + t;
            int cl = idx >> 6, hl = idx & 63;
            WlT[(size_t)(r * EMB_ + cb * 64 + cl) * H_ + hb * 64 + hl] = f2bf(tile[hl][cl]);
        }
    } else {
        // ---- Etgt gather + tgt_ids ----
        int b3 = blk - 776;
        int trip = b3 * 32 + (t >> 3);
        int u = t & 7;
        int i = trip >> 8, b = (trip >> 5) & 7, n = trip & 31;
        int id = nid[((b * S_ + i) * NN_ + n) * 2 + 1];
        if (u == 0) tgt_ids[trip] = id;
        const float4* src = (const float4*)(node_emb + (size_t)id * EMB_ + u * 32);
        unsigned short* dst = Etgt + (size_t)trip * EMB_ + u * 32;
#pragma unroll
        for (int q = 0; q < 4; ++q) {
            float4 f0 = src[2 * q], f1 = src[2 * q + 1];
            i32x4 o;
            o[0] = pack2bf(f0.x, f0.y); o[1] = pack2bf(f0.z, f0.w);
            o[2] = pack2bf(f1.x, f1.y); o[3] = pack2bf(f1.z, f1.w);
            *(i32x4*)(dst + q * 8) = o;
        }
    }
}

// ---------------------------------------------------------------------------
// proj (cb folded): proj[trip][r] = A2[pair][r*256..]·emb_src + e·wl_b_r
__global__ __launch_bounds__(512) void proj_kernel(
        const int* __restrict__ nid, const float* __restrict__ node_emb,
        const float* __restrict__ A2, const float* __restrict__ e_all,
        const float* __restrict__ wl_b, float* __restrict__ proj) {
    __shared__ float A_s[R_][EMB_];
    __shared__ float cb_s[R_];
    int pair = blockIdx.x;
    int t = threadIdx.x;
    int w = t >> 6, l = t & 63;
    int i = pair >> 3, b = pair & 7;
#pragma unroll
    for (int q = 0; q < 4; ++q) {
        int idx = q * 512 + t;
        A_s[idx >> 8][idx & 255] = A2[(size_t)pair * 2048 + idx];
    }
    {
        float p = 0.f;
#pragma unroll
        for (int k = 0; k < 8; ++k) {
            int h = l + 64 * k;
            p = fmaf(e_all[(size_t)pair * H_ + h], wl_b[(size_t)w * H_ + h], p);
        }
#pragma unroll
        for (int mask = 1; mask < 64; mask <<= 1) p += __shfl_xor(p, mask, 64);
        if (l == 0) cb_s[w] = p;
    }
    __syncthreads();
    float4 a4 = ((const float4*)A_s[w])[l];
    int id = nid[((b * S_ + i) * NN_ + 0) * 2 + 0];
    float4 em = ((const float4*)(node_emb + (size_t)id * EMB_))[l];
    for (int n = 0; n < NN_; ++n) {
        float4 cur = em;
        if (n < NN_ - 1) {
            id = nid[((b * S_ + i) * NN_ + n + 1) * 2 + 0];
            em = ((const float4*)(node_emb + (size_t)id * EMB_))[l];
        }
        float p = cur.x * a4.x + cur.y * a4.y + cur.z * a4.z + cur.w * a4.w;
#pragma unroll
        for (int off = 32; off; off >>= 1) p += __shfl_down(p, off, 64);
        if (l == 0) proj[((size_t)pair * NN_ + n) * R_ + w] = p + cb_s[w];
    }
}

// ---------------------------------------------------------------------------
// gemm_v3: nxt = ê @ W3^T, ê built on the fly (proj ⊗ emb), K=2112.
// r8 structure (512thr, BM128xBN256, LDS dbuf, 1 barrier/K-step, gelu_fast,
// cvt_pk staging). r11 edit: 2-deep global-load pipeline (register sets A/B,
// loads for ks+2 issued while ks computes and ks+1 stores).
__global__ __launch_bounds__(512) void gemm_v3(
        const unsigned short* __restrict__ W3, const unsigned short* __restrict__ Etgt,
        const int* __restrict__ tgt_ids, const float* __restrict__ proj,
        const float* __restrict__ bias_base, const float* __restrict__ pe,
        const float* __restrict__ node_bias, float* __restrict__ epart) {
    __shared__ unsigned short Als[2][128 * 64];   // 32 KB
    __shared__ unsigned short Bls[2][256 * 64];   // 64 KB
    __shared__ float proj_s[128 * R_];            // 4 KB
    __shared__ float base_s[256];
    __shared__ float red_s[128 * 4];
    __shared__ int   tgt_s[128];
    int blkM = blockIdx.x;        // 0..127
    int blkN = blockIdx.y;        // 0..1
    int trip0 = blkM * 128;
    int i_blk = blkM >> 1;
    int t = threadIdx.x, w = t >> 6, l = t & 63;
    int wm = w >> 2, wn = w & 3;

    proj_s[t] = proj[(size_t)trip0 * R_ + t];
    proj_s[t + 512] = proj[(size_t)trip0 * R_ + t + 512];
    if (t < 256) base_s[t] = bias_base[blkN * 256 + t] + pe[(i_blk + 1) * H_ + blkN * 256 + t];
    if (t < 128) tgt_s[t] = tgt_ids[trip0 + t];
    __syncthreads();

    int srw = t >> 3, sun = t & 7;
    f32x4 acc[4][4];
#pragma unroll
    for (int m = 0; m < 4; ++m)
#pragma unroll
        for (int n = 0; n < 4; ++n) acc[m][n] = (f32x4)0.f;

    i32x4 arA[2], brA[4], arB[2], brB[4];
#define A_LOAD(KS, AR)                                                        \
    if ((KS) < 32) {                                                          \
        int c_ = (((KS) & 3) << 6) + (sun << 3);                              \
        _Pragma("unroll")                                                     \
        for (int q = 0; q < 2; ++q)                                           \
            AR[q] = *(const i32x4*)(Etgt + (size_t)(trip0 + q * 64 + srw) * EMB_ + c_); \
    }
#define B_LOAD(KS, BR)                                                        \
    {                                                                         \
        _Pragma("unroll")                                                     \
        for (int q = 0; q < 4; ++q)                                           \
            BR[q] = *(const i32x4*)(W3 + (size_t)(blkN * 256 + q * 64 + srw) * KT3 + (KS) * 64 + sun * 8); \
    }
#define STORE(KS, AR, BR, BUF)                                                \
    {                                                                         \
        _Pragma("unroll")                                                     \
        for (int q = 0; q < 2; ++q) {                                         \
            int row = q * 64 + srw;                                           \
            i32x4 aval;                                                       \
            if ((KS) < 32) {                                                  \
                float pf = proj_s[row * R_ + ((KS) >> 2)];                    \
                aval = bf8_scale(AR[q], pf);                                  \
            } else if (sun == 0) {                                            \
                aval[0] = cvt_pk_bf16(proj_s[row * R_ + 0], proj_s[row * R_ + 1]); \
                aval[1] = cvt_pk_bf16(proj_s[row * R_ + 2], proj_s[row * R_ + 3]); \
                aval[2] = cvt_pk_bf16(proj_s[row * R_ + 4], proj_s[row * R_ + 5]); \
                aval[3] = cvt_pk_bf16(proj_s[row * R_ + 6], proj_s[row * R_ + 7]); \
            } else { aval[0] = 0; aval[1] = 0; aval[2] = 0; aval[3] = 0; }    \
            int ba = row * 128 + ((sun * 16) ^ ((row & 7) << 4));             \
            *(i32x4*)((char*)Als[BUF] + ba) = aval;                           \
        }                                                                     \
        _Pragma("unroll")                                                     \
        for (int q = 0; q < 4; ++q) {                                         \
            int row = q * 64 + srw;                                           \
            int ba = row * 128 + ((sun * 16) ^ ((row & 7) << 4));             \
            *(i32x4*)((char*)Bls[BUF] + ba) = BR[q];                          \
        }                                                                     \
    }
#define MFMA_PHASE(BUF)                                                       \
    {                                                                         \
        const char* Ab = (const char*)Als[BUF];                               \
        const char* Bb = (const char*)Bls[BUF];                               \
        _Pragma("unroll")                                                     \
        for (int kk2 = 0; kk2 < 2; ++kk2) {                                   \
            bf16x8 af[4], bf[4];                                              \
            int kb = kk2 * 64 + ((l >> 4) << 4);                              \
            _Pragma("unroll")                                                 \
            for (int mf = 0; mf < 4; ++mf) {                                  \
                int row = wm * 64 + mf * 16 + (l & 15);                       \
                af[mf] = *(const bf16x8*)(Ab + row * 128 + (kb ^ ((row & 7) << 4))); \
            }                                                                 \
            _Pragma("unroll")                                                 \
            for (int nf = 0; nf < 4; ++nf) {                                  \
                int row = wn * 64 + nf * 16 + (l & 15);                       \
                bf[nf] = *(const bf16x8*)(Bb + row * 128 + (kb ^ ((row & 7) << 4))); \
            }                                                                 \
            _Pragma("unroll")                                                 \
            for (int mf = 0; mf < 4; ++mf)                                    \
                _Pragma("unroll")                                             \
                for (int nf = 0; nf < 4; ++nf)                                \
                    acc[mf][nf] = __builtin_amdgcn_mfma_f32_16x16x32_bf16(    \
                        af[mf], bf[nf], acc[mf][nf], 0, 0, 0);                \
        }                                                                     \
    }

    // prologue: fill buf0 (ks=0), prefetch ks=1 into register set B
    A_LOAD(0, arA); B_LOAD(0, brA);
    STORE(0, arA, brA, 0);
    A_LOAD(1, arB); B_LOAD(1, brB);
    __syncthreads();

    // main loop: 16 unrolled pairs covering ks = 0..31, then final ks = 32.
    // iter ks: issue loads ks+2 -> freed set; MFMA buf[ks&1]; STORE ks+1.
    for (int ks = 0; ks < 32; ks += 2) {
        // parity 0
        if (ks + 2 < NS3) { A_LOAD(ks + 2, arA); B_LOAD(ks + 2, brA); }
        MFMA_PHASE(0);
        STORE(ks + 1, arB, brB, 1);
        __syncthreads();
        // parity 1
        if (ks + 3 < NS3) { A_LOAD(ks + 3, arB); B_LOAD(ks + 3, brB); }
        MFMA_PHASE(1);
        if (ks + 2 < NS3) STORE(ks + 2, arA, brA, 0);
        __syncthreads();
    }
    MFMA_PHASE(0);   // ks = 32
#undef A_LOAD
#undef B_LOAD
#undef STORE
#undef MFMA_PHASE

    int hl = l & 15, lq = l >> 4;
#pragma unroll
    for (int mf = 0; mf < 4; ++mf)
#pragma unroll
        for (int reg = 0; reg < 4; ++reg) {
            int tl = wm * 64 + mf * 16 + lq * 4 + reg;
            int tgt = tgt_s[tl];
            float s = 0.f;
#pragma unroll
            for (int nf = 0; nf < 4; ++nf) {
                int hloc = wn * 64 + nf * 16 + hl;
                int h = blkN * 256 + hloc;
                float val = fmaf(acc[mf][nf][reg], SCALE_,
                                 base_s[hloc] + node_bias[(size_t)tgt * H_ + h]);
                float o = gelu_fast(val);
                s = fmaf(o, o, s);
            }
            s += __shfl_xor(s, 1, 64);
            s += __shfl_xor(s, 2, 64);
            s += __shfl_xor(s, 4, 64);
            s += __shfl_xor(s, 8, 64);
            if (hl == 0) red_s[tl * 4 + wn] = s;
        }
    __syncthreads();
    if (t < 128) {
        float s = red_s[t * 4] + red_s[t * 4 + 1] + red_s[t * 4 + 2] + red_s[t * 4 + 3];
        epart[(size_t)(trip0 + t) * 2 + blkN] = s;
    }
}

// ---------------------------------------------------------------------------
// loss (with energy finalize folded in)
__global__ void loss_kernel(const float* __restrict__ epart, float* __restrict__ out) {
    __shared__ float red[8];
    int t = threadIdx.x;  // 512 pairs
    float en[NN_];
    float mx = -1e30f;
#pragma unroll
    for (int n = 0; n < NN_; ++n) {
        int trip = t * NN_ + n;
        en[n] = sqrtf(epart[(size_t)trip * 2] + epart[(size_t)trip * 2 + 1]);
        mx = fmaxf(mx, en[n]);
    }
    float s = 0.f;
#pragma unroll
    for (int n = 0; n < NN_; ++n) s += expf(en[n] - mx);
    float li = logf(s) + mx - en[0];
#pragma unroll
    for (int off = 32; off; off >>= 1) li += __shfl_down(li, off, 64);
    if ((t & 63) == 0) red[t >> 6] = li;
    __syncthreads();
    if (t == 0) {
        float tot = 0.f;
#pragma unroll
        for (int w = 0; w < 8; ++w) tot += red[w];
        out[0] = tot / 512.0f;
    }
}

// ---------------------------------------------------------------------------
extern "C" void kernel_launch(void* const* d_in, const int* in_sizes, int n_in,
                              void* d_out, int out_size, void* d_ws, size_t ws_size,
                              hipStream_t stream) {
    const int*   nid       = (const int*)d_in[0];
    const float* node_emb  = (const float*)d_in[1];
    const float* wl_w      = (const float*)d_in[2];
    const float* wl_b      = (const float*)d_in[3];
    const float* wr_w      = (const float*)d_in[4];
    const float* wr_b      = (const float*)d_in[5];
    const float* bias_base = (const float*)d_in[6];
    const float* node_bias = (const float*)d_in[7];
    const float* positions = (const float*)d_in[8];
    float* out = (float*)d_out;

    float* ws      = (float*)d_ws;
    float* pe      = ws;                        // 33280
    float* e_all   = pe + 65 * H_;              // 262144
    float* U0      = e_all + 512 * H_;          // 2097152
    float* V0      = U0 + 512 * 4096;           // 2097152
    float* A2      = V0 + 512 * 4096;           // 1048576
    float* proj    = A2 + 512 * 2048;           // 131072
    float* epart   = proj + NT_ * R_;           // 32768
    unsigned short* e_bf  = (unsigned short*)(epart + 2 * NT_);   // 262144 sh
    unsigned short* W3    = e_bf + 512 * H_;                      // 512*2112 sh
    unsigned short* Wl_bf = W3 + 512 * KT3;                       // 1048576 sh
    unsigned short* Wr_bf = Wl_bf + 4096 * EMB_;                  // 1048576 sh
    unsigned short* WlT   = Wr_bf + 4096 * EMB_;                  // 1048576 sh
    unsigned short* E0    = WlT + 2048 * H_;                      // 262144 sh
    unsigned short* Etgt  = E0 + 1024 * EMB_;                     // 4194304 sh
    int* tgt_ids = (int*)(Etgt + (size_t)NT_ * EMB_);             // 16384

    prep_all<<<4233, 256, 0, stream>>>(nid, node_emb, wl_w, wr_w, node_bias,
                                       pe, e_all, Wl_bf, Wr_bf, E0);
    gemm_nt<<<dim3(4, 32, 2), 256, 0, stream>>>(
        E0, Wl_bf, wl_b, U0,
        E0 + 512 * EMB_, Wr_bf, wr_b, V0, 256, 4096);
    seq_prep<<<8 + 512 + 256 + 512, 256, 0, stream>>>(
        nid, positions, U0, V0, bias_base, node_bias, pe, e_all, e_bf,
        wr_w, wr_b, W3, wl_w, WlT, node_emb, Etgt, tgt_ids);
    gemm_nt<<<dim3(4, 16, 1), 256, 0, stream>>>(
        e_bf, WlT, nullptr, A2, e_bf, WlT, nullptr, A2, 512, 2048);
    proj_kernel<<<512, 512, 0, stream>>>(nid, node_emb, A2, e_all, wl_b, proj);
    gemm_v3<<<dim3(128, 2), 512, 0, stream>>>(W3, Etgt, tgt_ids, proj,
                                              bias_base, pe, node_bias, epart);
    loss_kernel<<<1, 512, 0, stream>>>(epart, out);
}